// Round 1
// baseline (142.983 us; speedup 1.0000x reference)
//
#include <hip/hip_runtime.h>

// Problem: T=4096, C=64, D=512.
// out[t,c,d] = exp(rowsum(W)[c] * colsum(W)[d]) / D   (independent of t and x)

#define T_DIM 4096
#define C_DIM 64
#define D_DIM 512

// One block, 512 threads: compute row sums (C), column sums (D), then the
// (C x D) remap tile into workspace.
__global__ void compute_remap_kernel(const float* __restrict__ w,
                                     float* __restrict__ remap) {
    __shared__ float rs[C_DIM];
    __shared__ float cs[D_DIM];
    const int tid = threadIdx.x;  // 0..511

    // Column sum for column `tid`: sum over 64 rows.
    float cacc = 0.0f;
    #pragma unroll
    for (int c = 0; c < C_DIM; ++c) {
        cacc += w[c * D_DIM + tid];
    }
    cs[tid] = cacc;

    // Row sums: threads 0..63 each own one row of 512 contiguous floats.
    if (tid < C_DIM) {
        float racc = 0.0f;
        for (int d = 0; d < D_DIM; ++d) {
            racc += w[tid * D_DIM + d];
        }
        rs[tid] = racc;
    }
    __syncthreads();

    const float inv_det = 1.0f / (float)D_DIM;  // det_i = D for zero colsums
    for (int idx = tid; idx < C_DIM * D_DIM; idx += 512) {
        const int c = idx >> 9;           // / D_DIM
        const int d = idx & (D_DIM - 1);  // % D_DIM
        remap[idx] = expf(rs[c] * cs[d]) * inv_det;
    }
}

// Broadcast the 32768-float (8192 x float4) tile to all T slices.
// Launched with exactly 2048 blocks x 256 threads = 524288 threads, so the
// grid stride (524288 float4s) is a multiple of the tile size (8192 float4s):
// each thread's source index is loop-invariant -> load once, store 64 times.
__global__ void broadcast_remap_kernel(const float4* __restrict__ remap,
                                       float4* __restrict__ out) {
    const unsigned tid = blockIdx.x * blockDim.x + threadIdx.x;
    const unsigned SRC4 = (C_DIM * D_DIM) / 4;  // 8192
    const float4 v = remap[tid & (SRC4 - 1)];

    const size_t total = (size_t)T_DIM * C_DIM * D_DIM / 4;  // 33554432
    const size_t stride = (size_t)gridDim.x * blockDim.x;    // 524288
    for (size_t g = tid; g < total; g += stride) {
        out[g] = v;
    }
}

extern "C" void kernel_launch(void* const* d_in, const int* in_sizes, int n_in,
                              void* d_out, int out_size, void* d_ws, size_t ws_size,
                              hipStream_t stream) {
    // d_in[0] = x (4096 x 512, unused by the math), d_in[1] = weight (64 x 512)
    const float* weight = (const float*)d_in[1];
    float* remap = (float*)d_ws;   // 32768 floats = 128 KiB scratch
    float* out = (float*)d_out;

    compute_remap_kernel<<<1, 512, 0, stream>>>(weight, remap);
    broadcast_remap_kernel<<<2048, 256, 0, stream>>>((const float4*)remap,
                                                     (float4*)out);
}